// Round 6
// baseline (347.767 us; speedup 1.0000x reference)
//
#include <hip/hip_runtime.h>

#define NFEAT 128
#define NPART 64   // atomic partitions

typedef unsigned int uint;
typedef __attribute__((ext_vector_type(8))) short short8v;
typedef __attribute__((ext_vector_type(8))) unsigned short ushort8v;
typedef __attribute__((ext_vector_type(4))) float floatx4;

__device__ inline float bf2f(unsigned short u) {
    return __uint_as_float(((uint)u) << 16);
}
__device__ inline unsigned short f2bf(float f) {   // round-nearest-even
    uint u = __float_as_uint(f);
    return (unsigned short)((u + 0x7fffu + ((u >> 16) & 1u)) >> 16);
}

// ---------------- degree count ----------------
__global__ void count_deg_kernel(const int* __restrict__ dst, int* __restrict__ deg, int E) {
    int e = blockIdx.x * blockDim.x + threadIdx.x;
    if (e < E) atomicAdd(&deg[dst[e]], 1);
}

// ---------------- dinv + per-graph node counts (partitioned atomics) ----------------
__global__ void node_init_kernel(const int* __restrict__ deg, const int* __restrict__ batch,
                                 float* __restrict__ dinv, float* __restrict__ gcntp, int N) {
    int v = blockIdx.x * blockDim.x + threadIdx.x;
    if (v < N) {
        dinv[v] = rsqrtf((float)(deg[v] + 1));   // +1 self-loop
        atomicAdd(&gcntp[(v & (NPART - 1)) * 256 + batch[v]], 1.0f);
    }
}

// ---------------- multi-block scan, stage 1 ----------------
__global__ __launch_bounds__(256) void scan_partial_kernel(const int* __restrict__ deg,
                                                           int* __restrict__ bsum, int n) {
    __shared__ int sm[4];
    const int tid = threadIdx.x;
    const int base = blockIdx.x * 1024 + tid * 4;
    int s = 0;
#pragma unroll
    for (int j = 0; j < 4; ++j) s += (base + j < n) ? deg[base + j] : 0;
#pragma unroll
    for (int off = 32; off; off >>= 1) s += __shfl_down(s, off);
    if ((tid & 63) == 0) sm[tid >> 6] = s;
    __syncthreads();
    if (tid == 0) bsum[blockIdx.x] = sm[0] + sm[1] + sm[2] + sm[3];
}

// ---------------- stage 2: exclusive scan of block sums ----------------
__global__ __launch_bounds__(64) void scan_offsets_kernel(const int* __restrict__ bsum,
                                                          int* __restrict__ boff, int nb) {
    const int l = threadIdx.x;
    int orig = (l < nb) ? bsum[l] : 0;
    int v = orig;
#pragma unroll
    for (int off = 1; off < 64; off <<= 1) {
        int t = __shfl_up(v, off);
        if (l >= off) v += t;
    }
    if (l < nb) boff[l] = v - orig;
}

// ---------------- stage 3: final scan ----------------
__global__ __launch_bounds__(256) void scan_final_kernel(const int* __restrict__ deg,
                                                         const int* __restrict__ boff,
                                                         int* __restrict__ row_start,
                                                         int* __restrict__ cursor, int n) {
    __shared__ int wsum[4];
    const int tid = threadIdx.x;
    const int lane = tid & 63;
    const int w = tid >> 6;
    const int base = blockIdx.x * 1024 + tid * 4;
    int v[4];
    int s = 0;
#pragma unroll
    for (int j = 0; j < 4; ++j) {
        v[j] = (base + j < n) ? deg[base + j] : 0;
        s += v[j];
    }
    int incl = s;
#pragma unroll
    for (int off = 1; off < 64; off <<= 1) {
        int t = __shfl_up(incl, off);
        if (lane >= off) incl += t;
    }
    if (lane == 63) wsum[w] = incl;
    __syncthreads();
    int woff = 0;
    for (int i = 0; i < w; ++i) woff += wsum[i];
    int run = boff[blockIdx.x] + woff + (incl - s);
#pragma unroll
    for (int j = 0; j < 4; ++j) {
        if (base + j < n) { row_start[base + j] = run; cursor[base + j] = run; }
        run += v[j];
    }
}

// ---------------- CSR fill ----------------
__global__ void csr_fill_kernel(const int* __restrict__ src, const int* __restrict__ dst,
                                int* __restrict__ cursor, int* __restrict__ csr_src, int E) {
    int e = blockIdx.x * blockDim.x + threadIdx.x;
    if (e < E) {
        int pos = atomicAdd(&cursor[dst[e]], 1);
        csr_src[pos] = src[e];
    }
}

// ================= MFMA GEMM (layer 1): split-precision bf16, chunked output =================
// out layout: [ch][N][32] bf16 (chunk ch = features 32ch..32ch+31)
__global__ __launch_bounds__(256) void gemm1_mfma_kernel(const float* __restrict__ X,
                                                         const float* __restrict__ W,
                                                         const float* __restrict__ dinv,
                                                         unsigned short* __restrict__ out,
                                                         int nrows) {
    __shared__ unsigned short xs_hi[64][72], xs_lo[64][72];
    __shared__ unsigned short wt_hi[128][72], wt_lo[128][72];
    const int tid = threadIdx.x;
    const int w = tid >> 6, lane = tid & 63;
    const int nl = lane & 15, kg = lane >> 4;
    const int row0 = blockIdx.x * 64;

    floatx4 acc[8];
#pragma unroll
    for (int nt = 0; nt < 8; ++nt) acc[nt] = (floatx4){0.f, 0.f, 0.f, 0.f};

    for (int p = 0; p < 2; ++p) {
        __syncthreads();
        for (int idx = tid; idx < 64 * 16; idx += 256) {
            int r = idx >> 4, q = idx & 15;
            float4 v = make_float4(0.f, 0.f, 0.f, 0.f);
            if (row0 + r < nrows)
                v = ((const float4*)(X + (size_t)(row0 + r) * NFEAT + p * 64))[q];
            ushort4 h, l;
            h.x = f2bf(v.x); l.x = f2bf(v.x - bf2f(h.x));
            h.y = f2bf(v.y); l.y = f2bf(v.y - bf2f(h.y));
            h.z = f2bf(v.z); l.z = f2bf(v.z - bf2f(h.z));
            h.w = f2bf(v.w); l.w = f2bf(v.w - bf2f(h.w));
            *(ushort4*)&xs_hi[r][q * 4] = h;
            *(ushort4*)&xs_lo[r][q * 4] = l;
        }
        for (int idx = tid; idx < 64 * 32; idx += 256) {
            int kk = idx >> 5, q = idx & 31;
            float4 v = ((const float4*)(W + (size_t)(p * 64 + kk) * NFEAT))[q];
            int n = q * 4;
            unsigned short h;
            h = f2bf(v.x); wt_hi[n + 0][kk] = h; wt_lo[n + 0][kk] = f2bf(v.x - bf2f(h));
            h = f2bf(v.y); wt_hi[n + 1][kk] = h; wt_lo[n + 1][kk] = f2bf(v.y - bf2f(h));
            h = f2bf(v.z); wt_hi[n + 2][kk] = h; wt_lo[n + 2][kk] = f2bf(v.z - bf2f(h));
            h = f2bf(v.w); wt_hi[n + 3][kk] = h; wt_lo[n + 3][kk] = f2bf(v.w - bf2f(h));
        }
        __syncthreads();
#pragma unroll
        for (int kc = 0; kc < 2; ++kc) {
            const int k8 = kc * 32 + kg * 8;
            short8v ah = *(const short8v*)&xs_hi[w * 16 + nl][k8];
            short8v al = *(const short8v*)&xs_lo[w * 16 + nl][k8];
#pragma unroll
            for (int nt = 0; nt < 8; ++nt) {
                short8v bh = *(const short8v*)&wt_hi[nt * 16 + nl][k8];
                short8v bl = *(const short8v*)&wt_lo[nt * 16 + nl][k8];
                acc[nt] = __builtin_amdgcn_mfma_f32_16x16x32_bf16(ah, bh, acc[nt], 0, 0, 0);
                acc[nt] = __builtin_amdgcn_mfma_f32_16x16x32_bf16(al, bh, acc[nt], 0, 0, 0);
                acc[nt] = __builtin_amdgcn_mfma_f32_16x16x32_bf16(ah, bl, acc[nt], 0, 0, 0);
            }
        }
    }
    const int rbase = row0 + w * 16 + kg * 4;
#pragma unroll
    for (int reg = 0; reg < 4; ++reg) {
        int grow = rbase + reg;
        if (grow < nrows) {
            float dv = dinv[grow];
#pragma unroll
            for (int nt = 0; nt < 8; ++nt)
                out[((size_t)(nt >> 1) * nrows + grow) * 32 + (nt & 1) * 16 + nl] =
                    f2bf(acc[nt][reg] * dv);
        }
    }
}

// ================= MFMA GEMM (layer 2): X chunked bf16, W f32->hi/lo, chunked output ==========
__global__ __launch_bounds__(256) void gemm2_mfma_kernel(const unsigned short* __restrict__ X,
                                                         const float* __restrict__ W,
                                                         const float* __restrict__ dinv,
                                                         unsigned short* __restrict__ out,
                                                         int nrows) {
    __shared__ unsigned short xs[64][72];
    __shared__ unsigned short wt_hi[128][72], wt_lo[128][72];
    const int tid = threadIdx.x;
    const int w = tid >> 6, lane = tid & 63;
    const int nl = lane & 15, kg = lane >> 4;
    const int row0 = blockIdx.x * 64;

    floatx4 acc[8];
#pragma unroll
    for (int nt = 0; nt < 8; ++nt) acc[nt] = (floatx4){0.f, 0.f, 0.f, 0.f};

    for (int p = 0; p < 2; ++p) {
        __syncthreads();
        // stage X chunk: k = p*64 + q*8.. -> chunk ch = p*2 + (q>>2), offset (q&3)*8
        for (int idx = tid; idx < 64 * 8; idx += 256) {
            int r = idx >> 3, q = idx & 7;
            int ch = p * 2 + (q >> 2);
            short8v v = {0, 0, 0, 0, 0, 0, 0, 0};
            if (row0 + r < nrows)
                v = *(const short8v*)(X + ((size_t)ch * nrows + row0 + r) * 32 + (q & 3) * 8);
            *(short8v*)&xs[r][q * 8] = v;
        }
        for (int idx = tid; idx < 64 * 32; idx += 256) {
            int kk = idx >> 5, q = idx & 31;
            float4 v = ((const float4*)(W + (size_t)(p * 64 + kk) * NFEAT))[q];
            int n = q * 4;
            unsigned short h;
            h = f2bf(v.x); wt_hi[n + 0][kk] = h; wt_lo[n + 0][kk] = f2bf(v.x - bf2f(h));
            h = f2bf(v.y); wt_hi[n + 1][kk] = h; wt_lo[n + 1][kk] = f2bf(v.y - bf2f(h));
            h = f2bf(v.z); wt_hi[n + 2][kk] = h; wt_lo[n + 2][kk] = f2bf(v.z - bf2f(h));
            h = f2bf(v.w); wt_hi[n + 3][kk] = h; wt_lo[n + 3][kk] = f2bf(v.w - bf2f(h));
        }
        __syncthreads();
#pragma unroll
        for (int kc = 0; kc < 2; ++kc) {
            const int k8 = kc * 32 + kg * 8;
            short8v a = *(const short8v*)&xs[w * 16 + nl][k8];
#pragma unroll
            for (int nt = 0; nt < 8; ++nt) {
                short8v bh = *(const short8v*)&wt_hi[nt * 16 + nl][k8];
                short8v bl = *(const short8v*)&wt_lo[nt * 16 + nl][k8];
                acc[nt] = __builtin_amdgcn_mfma_f32_16x16x32_bf16(a, bh, acc[nt], 0, 0, 0);
                acc[nt] = __builtin_amdgcn_mfma_f32_16x16x32_bf16(a, bl, acc[nt], 0, 0, 0);
            }
        }
    }
    const int rbase = row0 + w * 16 + kg * 4;
#pragma unroll
    for (int reg = 0; reg < 4; ++reg) {
        int grow = rbase + reg;
        if (grow < nrows) {
            float dv = dinv[grow];
#pragma unroll
            for (int nt = 0; nt < 8; ++nt)
                out[((size_t)(nt >> 1) * nrows + grow) * 32 + (nt & 1) * 16 + nl] =
                    f2bf(acc[nt][reg] * dv);
        }
    }
}

// ---------------- chunked aggregation core ----------------
// Wave = 1 node, chunk ch = blockIdx.y. Lane: eg = lane>>2 (16 edge groups), q = lane&3.
// Row = 64B (32 bf16); lane loads its 16B quarter. Table per chunk = 3.2MB (L2-resident).
__device__ inline void agg_core(const unsigned short* __restrict__ tab,
                                const int* __restrict__ csr_src,
                                int v, int s, int d, int eg, int q, float acc[8]) {
    const int qo = q * 8;
    if (eg == 0) {   // self loop
        ushort8v r = *(const ushort8v*)(tab + (size_t)v * 32 + qo);
#pragma unroll
        for (int j = 0; j < 8; ++j) acc[j] += bf2f(r[j]);
    }
    int i = eg;
    for (; i + 16 < d; i += 32) {
        int u0 = csr_src[s + i];
        int u1 = csr_src[s + i + 16];
        ushort8v r0 = *(const ushort8v*)(tab + (size_t)u0 * 32 + qo);
        ushort8v r1 = *(const ushort8v*)(tab + (size_t)u1 * 32 + qo);
#pragma unroll
        for (int j = 0; j < 8; ++j) acc[j] += bf2f(r0[j]) + bf2f(r1[j]);
    }
    if (i < d) {
        int u = csr_src[s + i];
        ushort8v r = *(const ushort8v*)(tab + (size_t)u * 32 + qo);
#pragma unroll
        for (int j = 0; j < 8; ++j) acc[j] += bf2f(r[j]);
    }
    // reduce across the 16 edge groups (same quarter q)
#pragma unroll
    for (int mask = 4; mask < 64; mask <<= 1)
#pragma unroll
        for (int j = 0; j < 8; ++j) acc[j] += __shfl_xor(acc[j], mask);
}

// ---------------- aggregation + relu (layer 1), chunked ----------------
__global__ __launch_bounds__(256) void agg_relu_kernel(const unsigned short* __restrict__ hpc,
                                                       const int* __restrict__ row_start,
                                                       const int* __restrict__ deg,
                                                       const int* __restrict__ csr_src,
                                                       const float* __restrict__ dinv,
                                                       const float* __restrict__ bias,
                                                       unsigned short* __restrict__ out, int N) {
    const int v = blockIdx.x * 4 + (threadIdx.x >> 6);
    if (v >= N) return;
    const int ch = blockIdx.y;
    const int lane = threadIdx.x & 63;
    const int eg = lane >> 2, q = lane & 3;
    const unsigned short* tab = hpc + (size_t)ch * N * 32;
    float acc[8] = {0, 0, 0, 0, 0, 0, 0, 0};
    agg_core(tab, csr_src, v, row_start[v], deg[v], eg, q, acc);
    if (eg == 0) {
        const float dv = dinv[v];
        const float* bp = bias + ch * 32 + q * 8;
        float4 bA = *(const float4*)bp;
        float4 bB = *(const float4*)(bp + 4);
        ushort8v o;
        o[0] = f2bf(fmaxf(fmaf(acc[0], dv, bA.x), 0.f));
        o[1] = f2bf(fmaxf(fmaf(acc[1], dv, bA.y), 0.f));
        o[2] = f2bf(fmaxf(fmaf(acc[2], dv, bA.z), 0.f));
        o[3] = f2bf(fmaxf(fmaf(acc[3], dv, bA.w), 0.f));
        o[4] = f2bf(fmaxf(fmaf(acc[4], dv, bB.x), 0.f));
        o[5] = f2bf(fmaxf(fmaf(acc[5], dv, bB.y), 0.f));
        o[6] = f2bf(fmaxf(fmaf(acc[6], dv, bB.z), 0.f));
        o[7] = f2bf(fmaxf(fmaf(acc[7], dv, bB.w), 0.f));
        *(ushort8v*)(out + ((size_t)ch * N + v) * 32 + q * 8) = o;
    }
}

// ---------------- aggregation + relu + dot(lin_W) + partitioned pool (layer 2), chunked -------
__global__ __launch_bounds__(256) void agg_pool_kernel(const unsigned short* __restrict__ hpc,
                                                       const int* __restrict__ row_start,
                                                       const int* __restrict__ deg,
                                                       const int* __restrict__ csr_src,
                                                       const float* __restrict__ dinv,
                                                       const float* __restrict__ bias,
                                                       const float* __restrict__ linW,
                                                       const int* __restrict__ batch,
                                                       float* __restrict__ gpart, int N) {
    const int v = blockIdx.x * 4 + (threadIdx.x >> 6);
    if (v >= N) return;
    const int ch = blockIdx.y;
    const int lane = threadIdx.x & 63;
    const int eg = lane >> 2, q = lane & 3;
    const unsigned short* tab = hpc + (size_t)ch * N * 32;
    float acc[8] = {0, 0, 0, 0, 0, 0, 0, 0};
    agg_core(tab, csr_src, v, row_start[v], deg[v], eg, q, acc);
    const float dv = dinv[v];
    const float* bp = bias + ch * 32 + q * 8;
    const float* lp = linW + ch * 32 + q * 8;
    float4 bA = *(const float4*)bp;
    float4 bB = *(const float4*)(bp + 4);
    float4 lA = *(const float4*)lp;
    float4 lB = *(const float4*)(lp + 4);
    float sc = fmaxf(fmaf(acc[0], dv, bA.x), 0.f) * lA.x
             + fmaxf(fmaf(acc[1], dv, bA.y), 0.f) * lA.y
             + fmaxf(fmaf(acc[2], dv, bA.z), 0.f) * lA.z
             + fmaxf(fmaf(acc[3], dv, bA.w), 0.f) * lA.w
             + fmaxf(fmaf(acc[4], dv, bB.x), 0.f) * lB.x
             + fmaxf(fmaf(acc[5], dv, bB.y), 0.f) * lB.y
             + fmaxf(fmaf(acc[6], dv, bB.z), 0.f) * lB.z
             + fmaxf(fmaf(acc[7], dv, bB.w), 0.f) * lB.w;
    sc += __shfl_xor(sc, 1);
    sc += __shfl_xor(sc, 2);
    if (lane == 0) atomicAdd(&gpart[(v & (NPART - 1)) * 256 + batch[v]], sc);
}

// ---------------- finalize: reduce partitions ----------------
__global__ void finalize_kernel(const float* __restrict__ gpart, const float* __restrict__ gcntp,
                                const float* __restrict__ linb, float* __restrict__ out, int G) {
    int g = threadIdx.x;
    if (g < G) {
        float s = 0.f, c = 0.f;
        for (int p = 0; p < NPART; ++p) {
            s += gpart[p * 256 + g];
            c += gcntp[p * 256 + g];
        }
        out[g] = s / fmaxf(c, 1.0f) + linb[0];
    }
}

extern "C" void kernel_launch(void* const* d_in, const int* in_sizes, int n_in,
                              void* d_out, int out_size, void* d_ws, size_t ws_size,
                              hipStream_t stream) {
    const float* x    = (const float*)d_in[0];
    const int*   eidx = (const int*)d_in[1];
    const int*   batch= (const int*)d_in[2];
    const float* W1   = (const float*)d_in[3];
    const float* b1   = (const float*)d_in[4];
    const float* W2   = (const float*)d_in[5];
    const float* b2   = (const float*)d_in[6];
    const float* linW = (const float*)d_in[7];
    const float* linb = (const float*)d_in[8];
    float* out = (float*)d_out;

    const int N = in_sizes[0] / NFEAT;   // 50000
    const int E = in_sizes[1] / 2;       // 800000
    const int G = out_size;              // 256
    const int* src = eidx;
    const int* dst = eidx + E;
    const int NB = (N + 1023) / 1024;

    // workspace layout
    char* p = (char*)d_ws;
    unsigned short* hpBf = (unsigned short*)p; p += (size_t)N * NFEAT * sizeof(unsigned short); // chunked gemm out
    unsigned short* h1Bf = (unsigned short*)p; p += (size_t)N * NFEAT * sizeof(unsigned short); // chunked layer-1 act
    int*   csr_src  = (int*)p;   p += (size_t)E * sizeof(int);
    int*   row_start= (int*)p;   p += (size_t)(N + 4) * sizeof(int);
    int*   cursor   = (int*)p;   p += (size_t)N * sizeof(int);
    float* dinv     = (float*)p; p += (size_t)N * sizeof(float);
    int*   deg      = (int*)p;   p += (size_t)N * sizeof(int);
    float* gpart    = (float*)p; p += (size_t)NPART * 256 * sizeof(float);
    float* gcntp    = (float*)p; p += (size_t)NPART * 256 * sizeof(float);
    int*   bsum     = (int*)p;   p += 64 * sizeof(int);
    int*   boff     = (int*)p;   p += 64 * sizeof(int);
    (void)ws_size; (void)n_in;

    // zero deg + gpart + gcntp (contiguous)
    hipMemsetAsync(deg, 0, ((size_t)N + 2 * NPART * 256) * sizeof(float), stream);

    count_deg_kernel<<<(E + 255) / 256, 256, 0, stream>>>(dst, deg, E);
    node_init_kernel<<<(N + 255) / 256, 256, 0, stream>>>(deg, batch, dinv, gcntp, N);
    scan_partial_kernel<<<NB, 256, 0, stream>>>(deg, bsum, N);
    scan_offsets_kernel<<<1, 64, 0, stream>>>(bsum, boff, NB);
    scan_final_kernel<<<NB, 256, 0, stream>>>(deg, boff, row_start, cursor, N);
    csr_fill_kernel<<<(E + 255) / 256, 256, 0, stream>>>(src, dst, cursor, csr_src, E);

    dim3 agrid((N + 3) / 4, 4);
    // layer 1
    gemm1_mfma_kernel<<<(N + 63) / 64, 256, 0, stream>>>(x, W1, dinv, hpBf, N);
    agg_relu_kernel<<<agrid, 256, 0, stream>>>(hpBf, row_start, deg, csr_src, dinv, b1, h1Bf, N);
    // layer 2
    gemm2_mfma_kernel<<<(N + 63) / 64, 256, 0, stream>>>(h1Bf, W2, dinv, hpBf, N);
    agg_pool_kernel<<<agrid, 256, 0, stream>>>(hpBf, row_start, deg, csr_src, dinv, b2, linW,
                                               batch, gpart, N);
    finalize_kernel<<<1, 256, 0, stream>>>(gpart, gcntp, linb, out, G);
}